// Round 11
// baseline (171.020 us; speedup 1.0000x reference)
//
#include <hip/hip_runtime.h>
#include <math.h>

#define EMBED 512
#define HD 256
#define FR 12
#define NV 64
#define NT_TOK 4096
#define NV_TOK 768

typedef __attribute__((ext_vector_type(8))) short short8;
typedef __attribute__((ext_vector_type(4))) float f32x4;

__device__ __forceinline__ unsigned int f2bf(float f) {
  unsigned int u = __float_as_uint(f);
  u += 0x7FFFu + ((u >> 16) & 1u);   // RNE
  return u >> 16;
}
__device__ __forceinline__ void async_cp16(void* lds, const void* g) {
  __builtin_amdgcn_global_load_lds(
      (const __attribute__((address_space(1))) void*)g,
      (__attribute__((address_space(3))) void*)lds, 16, 0, 0);
}

// ===== 64x64 GEMM core: BK=64, 4 waves of 32x32, dbuf 1-sync ===============
__device__ __forceinline__ void gemm64_core(
    const unsigned short* __restrict__ Ab, int lda,
    const unsigned short* __restrict__ Bb, int ldb,
    int m0, int n0, int K,
    unsigned short* __restrict__ As, unsigned short* __restrict__ Bs,
    f32x4 acc[2][2]) {
  int tid = threadIdx.x;
  int w = tid >> 6, lane = tid & 63;
  int lr = lane & 15, quad = lane >> 4;
  int wm = (w >> 1) * 32, wn = (w & 1) * 32;
  int rowS[2], cgS[2];
  #pragma unroll
  for (int i = 0; i < 2; ++i) {
    int s = tid + i * 256;
    rowS[i] = s >> 3; cgS[i] = (s & 7) ^ (rowS[i] & 7);
  }
  int nk = K >> 6;
  #pragma unroll
  for (int i = 0; i < 2; ++i) {
    async_cp16(&As[(tid + i * 256) * 8],
               Ab + (size_t)(m0 + rowS[i]) * lda + cgS[i] * 8);
    async_cp16(&Bs[(tid + i * 256) * 8],
               Bb + (size_t)(n0 + rowS[i]) * ldb + cgS[i] * 8);
  }
  for (int k = 0; k < nk; ++k) {
    int cur = k & 1;
    __syncthreads();
    if (k + 1 < nk) {
      int nxt = cur ^ 1, koff = (k + 1) << 6;
      #pragma unroll
      for (int i = 0; i < 2; ++i) {
        async_cp16(&As[nxt * 4096 + (tid + i * 256) * 8],
                   Ab + (size_t)(m0 + rowS[i]) * lda + koff + cgS[i] * 8);
        async_cp16(&Bs[nxt * 4096 + (tid + i * 256) * 8],
                   Bb + (size_t)(n0 + rowS[i]) * ldb + koff + cgS[i] * 8);
      }
    }
    const unsigned short* Ac = As + cur * 4096;
    const unsigned short* Bc = Bs + cur * 4096;
    #pragma unroll
    for (int kk = 0; kk < 2; ++kk) {
      int sw = ((kk * 4 + quad) ^ (lr & 7)) * 8;
      short8 a0 = *(const short8*)&Ac[(wm + lr) * 64 + sw];
      short8 a1 = *(const short8*)&Ac[(wm + 16 + lr) * 64 + sw];
      short8 b0 = *(const short8*)&Bc[(wn + lr) * 64 + sw];
      short8 b1 = *(const short8*)&Bc[(wn + 16 + lr) * 64 + sw];
      acc[0][0] = __builtin_amdgcn_mfma_f32_16x16x32_bf16(a0, b0, acc[0][0], 0, 0, 0);
      acc[0][1] = __builtin_amdgcn_mfma_f32_16x16x32_bf16(a0, b1, acc[0][1], 0, 0, 0);
      acc[1][0] = __builtin_amdgcn_mfma_f32_16x16x32_bf16(a1, b0, acc[1][0], 0, 0, 0);
      acc[1][1] = __builtin_amdgcn_mfma_f32_16x16x32_bf16(a1, b1, acc[1][1], 0, 0, 0);
    }
  }
}

// ===== 64x32 GEMM core: BK=64, 4 waves of 32x16 (higher-TLP variant) =======
// acc[2]: 2 m-frags x 1 n-frag per wave. wm=(w>>1)*32, wn=(w&1)*16.
__device__ __forceinline__ void gemm64x32_core(
    const unsigned short* __restrict__ Ab, int lda,
    const unsigned short* __restrict__ Bb, int ldb,
    int m0, int n0, int K,
    unsigned short* __restrict__ As, unsigned short* __restrict__ Bs,
    f32x4 acc[2]) {
  int tid = threadIdx.x;
  int w = tid >> 6, lane = tid & 63;
  int lr = lane & 15, quad = lane >> 4;
  int wm = (w >> 1) * 32, wn = (w & 1) * 16;
  int rowA[2], cgA[2];
  #pragma unroll
  for (int i = 0; i < 2; ++i) {
    int s = tid + i * 256;
    rowA[i] = s >> 3; cgA[i] = (s & 7) ^ (rowA[i] & 7);
  }
  int rowB = tid >> 3, cgB = (tid & 7) ^ (rowB & 7);
  int nk = K >> 6;
  #pragma unroll
  for (int i = 0; i < 2; ++i)
    async_cp16(&As[(tid + i * 256) * 8],
               Ab + (size_t)(m0 + rowA[i]) * lda + cgA[i] * 8);
  async_cp16(&Bs[tid * 8], Bb + (size_t)(n0 + rowB) * ldb + cgB * 8);
  for (int k = 0; k < nk; ++k) {
    int cur = k & 1;
    __syncthreads();
    if (k + 1 < nk) {
      int nxt = cur ^ 1, koff = (k + 1) << 6;
      #pragma unroll
      for (int i = 0; i < 2; ++i)
        async_cp16(&As[nxt * 4096 + (tid + i * 256) * 8],
                   Ab + (size_t)(m0 + rowA[i]) * lda + koff + cgA[i] * 8);
      async_cp16(&Bs[nxt * 2048 + tid * 8],
                 Bb + (size_t)(n0 + rowB) * ldb + koff + cgB * 8);
    }
    const unsigned short* Ac = As + cur * 4096;
    const unsigned short* Bc = Bs + cur * 2048;
    #pragma unroll
    for (int kk = 0; kk < 2; ++kk) {
      int sw = ((kk * 4 + quad) ^ (lr & 7)) * 8;
      short8 a0 = *(const short8*)&Ac[(wm + lr) * 64 + sw];
      short8 a1 = *(const short8*)&Ac[(wm + 16 + lr) * 64 + sw];
      short8 b0 = *(const short8*)&Bc[(wn + lr) * 64 + sw];
      acc[0] = __builtin_amdgcn_mfma_f32_16x16x32_bf16(a0, b0, acc[0], 0, 0, 0);
      acc[1] = __builtin_amdgcn_mfma_f32_16x16x32_bf16(a1, b0, acc[1], 0, 0, 0);
    }
  }
}

// ===== fused QKV projection (+ zero the LN2 stats buffer) ==================
__global__ __launch_bounds__(256, 4) void qkv_kernel(
    const unsigned short* __restrict__ tn, const unsigned short* __restrict__ vn,
    const unsigned short* __restrict__ Wq, const unsigned short* __restrict__ Wk,
    const unsigned short* __restrict__ Wv,
    const float* __restrict__ bq, const float* __restrict__ bk,
    const float* __restrict__ bv,
    unsigned short* __restrict__ Q, unsigned short* __restrict__ Kout,
    unsigned short* __restrict__ V, float* __restrict__ stats) {
  __shared__ __align__(16) unsigned short As[2 * 4096];
  __shared__ __align__(16) unsigned short Bs[2 * 4096];
  int bid = blockIdx.x;
  if (bid < 32) stats[bid * 256 + threadIdx.x] = 0.0f;  // 8192 floats
  const unsigned short *Ap, *Bp;
  const float* bias;
  unsigned short* outp;
  int m0, n0;
  if (bid < 512) {            // Q
    Ap = tn; Bp = Wq; bias = bq; outp = Q;
    m0 = (bid >> 3) * 64; n0 = (bid & 7) * 64;
  } else if (bid < 608) {     // K
    int i = bid - 512;
    Ap = vn; Bp = Wk; bias = bk; outp = Kout;
    m0 = (i >> 3) * 64; n0 = (i & 7) * 64;
  } else {                    // V
    int i = bid - 608;
    Ap = vn; Bp = Wv; bias = bv; outp = V;
    m0 = (i >> 3) * 64; n0 = (i & 7) * 64;
  }
  f32x4 acc[2][2] = {};
  gemm64_core(Ap, EMBED, Bp, EMBED, m0, n0, EMBED, As, Bs, acc);
  int w = threadIdx.x >> 6, lane = threadIdx.x & 63;
  int lr = lane & 15, quad = lane >> 4;
  int wm = (w >> 1) * 32, wn = (w & 1) * 32;
  #pragma unroll
  for (int j = 0; j < 2; ++j) {
    int col = n0 + wn + j * 16 + lr;
    float bvv = bias[col];
    #pragma unroll
    for (int i = 0; i < 2; ++i) {
      int rbase = m0 + wm + i * 16 + quad * 4;
      #pragma unroll
      for (int r = 0; r < 4; ++r)
        outp[(size_t)(rbase + r) * EMBED + col] =
            (unsigned short)f2bf(acc[i][j][r] + bvv);
    }
  }
}

// ===== S-GEMM + softmax -> P [4096][1536]; plus W2 = Wo_h @ V_h^T ==========
__global__ __launch_bounds__(256, 4) void sgemm_softmax(
    const unsigned short* __restrict__ Q, const unsigned short* __restrict__ Kb,
    const unsigned short* __restrict__ V, const unsigned short* __restrict__ Wo,
    unsigned short* __restrict__ P, unsigned short* __restrict__ W2) {
  __shared__ __align__(16) char smem[40960];
  int tid = threadIdx.x;
  int w = tid >> 6, lane = tid & 63;
  int lr = lane & 15, quad = lane >> 4;
  int bid = blockIdx.x;

  if (bid >= 1024) {  // ---- W2 job (64x64, K=256) ----
    int j = bid - 1024;
    int h = j / 96, i = j % 96;
    int m0 = (i / 12) * 64, n0 = (i % 12) * 64;
    unsigned short* As = (unsigned short*)smem;
    unsigned short* Bs = (unsigned short*)(smem + 16384);
    f32x4 acc[2][2] = {};
    gemm64_core(Wo + h * HD, EMBED, V + h * HD, EMBED, m0, n0, HD, As, Bs, acc);
    int wm = (w >> 1) * 32, wn = (w & 1) * 32;
    #pragma unroll
    for (int j2 = 0; j2 < 2; ++j2) {
      int col = n0 + wn + j2 * 16 + lr;
      #pragma unroll
      for (int i2 = 0; i2 < 2; ++i2) {
        int rbase = m0 + wm + i2 * 16 + quad * 4;
        #pragma unroll
        for (int r = 0; r < 4; ++r)
          W2[(size_t)(rbase + r) * 1536 + h * 768 + col] =
              (unsigned short)f2bf(acc[i2][j2][r]);
      }
    }
    return;
  }

  // ---- S-softmax job: 64x96 tile ----
  unsigned short* As = (unsigned short*)smem;            // 2 x 4096
  unsigned short* Bs = (unsigned short*)(smem + 16384);  // 2 x 6144
  int wm = (w >> 1) * 32, wn = (w & 1) * 48;
  int h = bid >> 9, rem = bid & 511;
  int m0 = (rem >> 3) * 64, n0 = (rem & 7) * 96;
  const unsigned short* Ab = Q + h * HD;
  const unsigned short* Bb = Kb + h * HD;
  int rowA[2], cgA[2], rowB[3], cgB[3];
  #pragma unroll
  for (int i = 0; i < 2; ++i) {
    int s = tid + i * 256;
    rowA[i] = s >> 3; cgA[i] = (s & 7) ^ (rowA[i] & 7);
  }
  #pragma unroll
  for (int i = 0; i < 3; ++i) {
    int s = tid + i * 256;
    rowB[i] = s >> 3; cgB[i] = (s & 7) ^ (rowB[i] & 7);
  }
  f32x4 acc[2][3] = {};
  const int nk = HD >> 6;  // 4
  #pragma unroll
  for (int i = 0; i < 2; ++i)
    async_cp16(&As[(tid + i * 256) * 8],
               Ab + (size_t)(m0 + rowA[i]) * EMBED + cgA[i] * 8);
  #pragma unroll
  for (int i = 0; i < 3; ++i)
    async_cp16(&Bs[(tid + i * 256) * 8],
               Bb + (size_t)(n0 + rowB[i]) * EMBED + cgB[i] * 8);
  for (int k = 0; k < nk; ++k) {
    int cur = k & 1;
    __syncthreads();
    if (k + 1 < nk) {
      int nxt = cur ^ 1, koff = (k + 1) << 6;
      #pragma unroll
      for (int i = 0; i < 2; ++i)
        async_cp16(&As[nxt * 4096 + (tid + i * 256) * 8],
                   Ab + (size_t)(m0 + rowA[i]) * EMBED + koff + cgA[i] * 8);
      #pragma unroll
      for (int i = 0; i < 3; ++i)
        async_cp16(&Bs[nxt * 6144 + (tid + i * 256) * 8],
                   Bb + (size_t)(n0 + rowB[i]) * EMBED + koff + cgB[i] * 8);
    }
    const unsigned short* Ac = As + cur * 4096;
    const unsigned short* Bc = Bs + cur * 6144;
    #pragma unroll
    for (int kk = 0; kk < 2; ++kk) {
      int sw = ((kk * 4 + quad) ^ (lr & 7)) * 8;
      short8 a0 = *(const short8*)&Ac[(wm + lr) * 64 + sw];
      short8 a1 = *(const short8*)&Ac[(wm + 16 + lr) * 64 + sw];
      short8 b0 = *(const short8*)&Bc[(wn + lr) * 64 + sw];
      short8 b1 = *(const short8*)&Bc[(wn + 16 + lr) * 64 + sw];
      short8 b2 = *(const short8*)&Bc[(wn + 32 + lr) * 64 + sw];
      acc[0][0] = __builtin_amdgcn_mfma_f32_16x16x32_bf16(a0, b0, acc[0][0], 0, 0, 0);
      acc[0][1] = __builtin_amdgcn_mfma_f32_16x16x32_bf16(a0, b1, acc[0][1], 0, 0, 0);
      acc[0][2] = __builtin_amdgcn_mfma_f32_16x16x32_bf16(a0, b2, acc[0][2], 0, 0, 0);
      acc[1][0] = __builtin_amdgcn_mfma_f32_16x16x32_bf16(a1, b0, acc[1][0], 0, 0, 0);
      acc[1][1] = __builtin_amdgcn_mfma_f32_16x16x32_bf16(a1, b1, acc[1][1], 0, 0, 0);
      acc[1][2] = __builtin_amdgcn_mfma_f32_16x16x32_bf16(a1, b2, acc[1][2], 0, 0, 0);
    }
  }
  __syncthreads();
  float* Sx = (float*)smem;  // [64][100]
  #pragma unroll
  for (int j = 0; j < 3; ++j) {
    int col = wn + j * 16 + lr;
    #pragma unroll
    for (int i = 0; i < 2; ++i) {
      int rbase = wm + i * 16 + quad * 4;
      #pragma unroll
      for (int r = 0; r < 4; ++r) Sx[(rbase + r) * 100 + col] = acc[i][j][r];
    }
  }
  __syncthreads();
  #pragma unroll
  for (int gi = 0; gi < 2; ++gi) {
    int g = tid * 2 + gi;
    int row = g >> 3, gr = g & 7;
    const float* sp = Sx + row * 100 + gr * 12;
    float v[12];
    float m = -1e30f;
    #pragma unroll
    for (int f = 0; f < FR; ++f) { v[f] = sp[f] * 0.0625f; m = fmaxf(m, v[f]); }
    float s = 0.f;
    #pragma unroll
    for (int f = 0; f < FR; ++f) { v[f] = __expf(v[f] - m); s += v[f]; }
    float inv = (1.0f / NV) / s;
    unsigned short* pp = P + (size_t)(m0 + row) * 1536 + h * 768 + n0 + gr * 12;
    #pragma unroll
    for (int ii = 0; ii < 6; ++ii) {
      unsigned int lo = f2bf(v[2 * ii] * inv), hi = f2bf(v[2 * ii + 1] * inv);
      *(unsigned int*)(pp + 2 * ii) = lo | (hi << 16);
    }
  }
}

// ===== PV+O GEMM (64x32 tiles, K=1536) + LN2-stats atomics =================
__global__ __launch_bounds__(256, 4) void gemm_pvo(
    const unsigned short* __restrict__ P, const unsigned short* __restrict__ W2,
    const float* __restrict__ bo, float* __restrict__ Ob,
    float* __restrict__ stats) {
  __shared__ __align__(16) unsigned short As[2 * 4096];
  __shared__ __align__(16) unsigned short Bs[2 * 2048];
  f32x4 acc[2] = {};
  int m0 = blockIdx.x * 64, n0 = blockIdx.y * 32;
  gemm64x32_core(P, 1536, W2, 1536, m0, n0, 1536, As, Bs, acc);
  int w = threadIdx.x >> 6, lane = threadIdx.x & 63;
  int lr = lane & 15, quad = lane >> 4;
  int wm = (w >> 1) * 32, wn = (w & 1) * 16;
  float rs[2][4] = {}, rq[2][4] = {};
  int col = n0 + wn + lr;
  float bv = bo[col];
  #pragma unroll
  for (int i = 0; i < 2; ++i) {
    int rbase = m0 + wm + i * 16 + quad * 4;
    #pragma unroll
    for (int r = 0; r < 4; ++r) {
      float v = acc[i][r] + bv;
      Ob[(size_t)(rbase + r) * EMBED + col] = v;
      rs[i][r] += v;
      rq[i][r] += v * v;
    }
  }
  #pragma unroll
  for (int off = 8; off > 0; off >>= 1) {
    #pragma unroll
    for (int i = 0; i < 2; ++i)
      #pragma unroll
      for (int r = 0; r < 4; ++r) {
        rs[i][r] += __shfl_down(rs[i][r], off, 16);
        rq[i][r] += __shfl_down(rq[i][r], off, 16);
      }
  }
  if (lr == 0) {
    #pragma unroll
    for (int i = 0; i < 2; ++i) {
      #pragma unroll
      for (int r = 0; r < 4; ++r) {
        int row = m0 + wm + i * 16 + quad * 4 + r;
        atomicAdd(&stats[row * 2], rs[i][r]);
        atomicAdd(&stats[row * 2 + 1], rq[i][r]);
      }
    }
  }
}

// ===== L-GEMM (64x32 tiles) with LN2 applied during A-staging ==============
__global__ __launch_bounds__(256, 4) void gemm_lnl(
    const float* __restrict__ Ob, const float* __restrict__ stats,
    const float* __restrict__ g2, const float* __restrict__ b2,
    const unsigned short* __restrict__ Wl, const float* __restrict__ bl,
    float* __restrict__ lin) {
  __shared__ __align__(16) unsigned short As[2 * 4096];
  __shared__ __align__(16) unsigned short Bs[2 * 2048];
  int tid = threadIdx.x;
  int w = tid >> 6, lane = tid & 63;
  int lr = lane & 15, quad = lane >> 4;
  int wm = (w >> 1) * 32, wn = (w & 1) * 16;
  int m0 = blockIdx.x * 64, n0 = blockIdx.y * 32;
  int rowA[2], cgA[2];
  float mu[2], rstd[2];
  #pragma unroll
  for (int i = 0; i < 2; ++i) {
    int s = tid + i * 256;
    rowA[i] = s >> 3; cgA[i] = (s & 7) ^ (rowA[i] & 7);
    float s1 = stats[(m0 + rowA[i]) * 2];
    float s2 = stats[(m0 + rowA[i]) * 2 + 1];
    float m = s1 * (1.0f / EMBED);
    mu[i] = m;
    rstd[i] = rsqrtf(s2 * (1.0f / EMBED) - m * m + 1e-5f);
  }
  int rowB = tid >> 3, cgB = (tid & 7) ^ (rowB & 7);
  f32x4 acc[2] = {};
  const int nk = EMBED >> 6;  // 8

  #define STAGE_A(buf, koff)                                                  \
    {                                                                         \
      _Pragma("unroll") for (int i = 0; i < 2; ++i) {                         \
        const float* src = Ob + (size_t)(m0 + rowA[i]) * EMBED + (koff) +     \
                           cgA[i] * 8;                                        \
        const float* gp = g2 + (koff) + cgA[i] * 8;                           \
        const float* bp = b2 + (koff) + cgA[i] * 8;                           \
        float4 x0 = *(const float4*)src;                                      \
        float4 x1 = *(const float4*)(src + 4);                                \
        float4 ga = *(const float4*)gp;                                       \
        float4 gb = *(const float4*)(gp + 4);                                 \
        float4 ba = *(const float4*)bp;                                       \
        float4 bb = *(const float4*)(bp + 4);                                 \
        float y0 = (x0.x - mu[i]) * rstd[i] * ga.x + ba.x;                    \
        float y1 = (x0.y - mu[i]) * rstd[i] * ga.y + ba.y;                    \
        float y2 = (x0.z - mu[i]) * rstd[i] * ga.z + ba.z;                    \
        float y3 = (x0.w - mu[i]) * rstd[i] * ga.w + ba.w;                    \
        float y4 = (x1.x - mu[i]) * rstd[i] * gb.x + bb.x;                    \
        float y5 = (x1.y - mu[i]) * rstd[i] * gb.y + bb.y;                    \
        float y6 = (x1.z - mu[i]) * rstd[i] * gb.z + bb.z;                    \
        float y7 = (x1.w - mu[i]) * rstd[i] * gb.w + bb.w;                    \
        uint4 pk;                                                             \
        pk.x = f2bf(y0) | (f2bf(y1) << 16);                                   \
        pk.y = f2bf(y2) | (f2bf(y3) << 16);                                   \
        pk.z = f2bf(y4) | (f2bf(y5) << 16);                                   \
        pk.w = f2bf(y6) | (f2bf(y7) << 16);                                   \
        *(uint4*)&As[(buf)*4096 + (tid + i * 256) * 8] = pk;                  \
      }                                                                       \
    }

  STAGE_A(0, 0)
  async_cp16(&Bs[tid * 8], Wl + (size_t)(n0 + rowB) * EMBED + cgB * 8);
  for (int k = 0; k < nk; ++k) {
    int cur = k & 1;
    __syncthreads();
    if (k + 1 < nk) {
      int nxt = cur ^ 1, koff = (k + 1) << 6;
      STAGE_A(nxt, koff)
      async_cp16(&Bs[nxt * 2048 + tid * 8],
                 Wl + (size_t)(n0 + rowB) * EMBED + koff + cgB * 8);
    }
    const unsigned short* Ac = As + cur * 4096;
    const unsigned short* Bc = Bs + cur * 2048;
    #pragma unroll
    for (int kk = 0; kk < 2; ++kk) {
      int sw = ((kk * 4 + quad) ^ (lr & 7)) * 8;
      short8 a0 = *(const short8*)&Ac[(wm + lr) * 64 + sw];
      short8 a1 = *(const short8*)&Ac[(wm + 16 + lr) * 64 + sw];
      short8 b0 = *(const short8*)&Bc[(wn + lr) * 64 + sw];
      acc[0] = __builtin_amdgcn_mfma_f32_16x16x32_bf16(a0, b0, acc[0], 0, 0, 0);
      acc[1] = __builtin_amdgcn_mfma_f32_16x16x32_bf16(a1, b0, acc[1], 0, 0, 0);
    }
  }
  int col = n0 + wn + lr;
  float bv = bl[col];
  #pragma unroll
  for (int i = 0; i < 2; ++i) {
    int rbase = m0 + wm + i * 16 + quad * 4;
    #pragma unroll
    for (int r = 0; r < 4; ++r)
      lin[(size_t)(rbase + r) * EMBED + col] = acc[i][r] + bv;
  }
  #undef STAGE_A
}

// ===== final: out = LN3( LN2(Ob) + lin ) ===================================
__global__ __launch_bounds__(256) void ln3_kernel(
    const float* __restrict__ Ob, const float* __restrict__ stats,
    const float* __restrict__ lin,
    const float* __restrict__ g2, const float* __restrict__ b2,
    const float* __restrict__ g3, const float* __restrict__ b3,
    float* __restrict__ out) {
  int row = blockIdx.x;
  int t = threadIdx.x;
  float s1 = stats[row * 2], s2v = stats[row * 2 + 1];
  float mu2 = s1 * (1.0f / EMBED);
  float rstd2 = rsqrtf(s2v * (1.0f / EMBED) - mu2 * mu2 + 1e-5f);
  const float* xr = Ob + (size_t)row * EMBED;
  const float* lr_ = lin + (size_t)row * EMBED;
  float v0 = (xr[t] - mu2) * rstd2 * g2[t] + b2[t] + lr_[t];
  float v1 = (xr[t + 256] - mu2) * rstd2 * g2[t + 256] + b2[t + 256] + lr_[t + 256];
  float s = v0 + v1;
  float sq = v0 * v0 + v1 * v1;
  #pragma unroll
  for (int off = 32; off > 0; off >>= 1) {
    s += __shfl_down(s, off, 64);
    sq += __shfl_down(sq, off, 64);
  }
  __shared__ float ss[4], ss2[4];
  __shared__ float mean_s, rstd_s;
  int wid = t >> 6;
  if ((t & 63) == 0) { ss[wid] = s; ss2[wid] = sq; }
  __syncthreads();
  if (t == 0) {
    float a = ss[0] + ss[1] + ss[2] + ss[3];
    float a2 = ss2[0] + ss2[1] + ss2[2] + ss2[3];
    float mean = a * (1.0f / EMBED);
    float var = a2 * (1.0f / EMBED) - mean * mean;
    mean_s = mean;
    rstd_s = rsqrtf(var + 1e-5f);
  }
  __syncthreads();
  float mean = mean_s, rstd = rstd_s;
  float* orow = out + (size_t)row * EMBED;
  orow[t] = (v0 - mean) * rstd * g3[t] + b3[t];
  orow[t + 256] = (v1 - mean) * rstd * g3[t + 256] + b3[t + 256];
}

// ===== LayerNorm row helper (for prep) =====================================
__device__ __forceinline__ void ln_row(
    const float* __restrict__ xr,
    const float* __restrict__ g, const float* __restrict__ b,
    unsigned short* __restrict__ outb) {
  int t = threadIdx.x;
  float v0 = xr[t], v1 = xr[t + 256];
  float s = v0 + v1;
  float s2 = v0 * v0 + v1 * v1;
  #pragma unroll
  for (int off = 32; off > 0; off >>= 1) {
    s += __shfl_down(s, off, 64);
    s2 += __shfl_down(s2, off, 64);
  }
  __shared__ float ss[4], ss2[4];
  __shared__ float mean_s, rstd_s;
  int wid = t >> 6;
  if ((t & 63) == 0) { ss[wid] = s; ss2[wid] = s2; }
  __syncthreads();
  if (t == 0) {
    float a = ss[0] + ss[1] + ss[2] + ss[3];
    float a2 = ss2[0] + ss2[1] + ss2[2] + ss2[3];
    float mean = a * (1.0f / EMBED);
    float var = a2 * (1.0f / EMBED) - mean * mean;
    mean_s = mean;
    rstd_s = rsqrtf(var + 1e-5f);
  }
  __syncthreads();
  float mean = mean_s, rstd = rstd_s;
  outb[t] = (unsigned short)f2bf((v0 - mean) * rstd * g[t] + b[t]);
  outb[t + 256] =
      (unsigned short)f2bf((v1 - mean) * rstd * g[t + 256] + b[t + 256]);
}

// ===== prep: weight fp32->bf16 + LN1 on text & video =======================
__global__ __launch_bounds__(256) void prep_kernel(
    const float* __restrict__ text, const float* __restrict__ video,
    const float* __restrict__ g, const float* __restrict__ b,
    const float* __restrict__ Wq, const float* __restrict__ Wk,
    const float* __restrict__ Wv, const float* __restrict__ Wo,
    const float* __restrict__ Wl, unsigned short* __restrict__ Wbf,
    unsigned short* __restrict__ tn, unsigned short* __restrict__ vn) {
  int bid = blockIdx.x;
  if (bid < 1280) {
    int i = bid * 256 + threadIdx.x;
    const float* srcs[5] = {Wq, Wk, Wv, Wo, Wl};
    const float* src = srcs[i >> 16];
    float4 v = ((const float4*)src)[i & 65535];
    uint2 o;
    o.x = f2bf(v.x) | (f2bf(v.y) << 16);
    o.y = f2bf(v.z) | (f2bf(v.w) << 16);
    ((uint2*)Wbf)[i] = o;
    return;
  }
  if (bid < 1280 + NT_TOK) {
    size_t row = bid - 1280;
    ln_row(text + row * EMBED, g, b, tn + row * EMBED);
  } else {
    size_t row = bid - (1280 + NT_TOK);
    ln_row(video + row * EMBED, g, b, vn + row * EMBED);
  }
}

// ===== launch ==============================================================
extern "C" void kernel_launch(void* const* d_in, const int* in_sizes, int n_in,
                              void* d_out, int out_size, void* d_ws, size_t ws_size,
                              hipStream_t stream) {
  (void)in_sizes; (void)n_in; (void)out_size; (void)ws_size;
  const float* text  = (const float*)d_in[0];
  const float* video = (const float*)d_in[1];
  const float* ln1_g = (const float*)d_in[2];
  const float* ln1_b = (const float*)d_in[3];
  const float* Wq = (const float*)d_in[4];
  const float* bq = (const float*)d_in[5];
  const float* Wk = (const float*)d_in[6];
  const float* bk = (const float*)d_in[7];
  const float* Wv = (const float*)d_in[8];
  const float* bv = (const float*)d_in[9];
  const float* Wo = (const float*)d_in[10];
  const float* bo = (const float*)d_in[11];
  const float* Wl = (const float*)d_in[12];
  const float* bl = (const float*)d_in[13];
  const float* ln2_g = (const float*)d_in[14];
  const float* ln2_b = (const float*)d_in[15];
  const float* ln3_g = (const float*)d_in[16];
  const float* ln3_b = (const float*)d_in[17];
  float* out = (float*)d_out;

  // ---- workspace layout (44.3 MB, no aliasing) ----
  char* base = (char*)d_ws;
  unsigned short* Wbf   = (unsigned short*)base;                // 2.62 MB
  unsigned short* Wq_bf = Wbf + 0 * 262144;
  unsigned short* Wk_bf = Wbf + 1 * 262144;
  unsigned short* Wv_bf = Wbf + 2 * 262144;
  unsigned short* Wo_bf = Wbf + 3 * 262144;
  unsigned short* Wl_bf = Wbf + 4 * 262144;
  unsigned short* W2    = (unsigned short*)(base + 2621440);    // 512x1536
  float*          stats = (float*)(base + 4194304);             // 4096x2
  unsigned short* tn_bf = (unsigned short*)(base + 4227072);    // 4096x512
  unsigned short* vn_bf = (unsigned short*)(base + 8421376);    // 768x512
  unsigned short* Q_bf  = (unsigned short*)(base + 9207808);    // 4096x512
  unsigned short* K_bf  = (unsigned short*)(base + 13402112);   // 768x512
  unsigned short* V_bf  = (unsigned short*)(base + 14188544);   // 768x512
  unsigned short* P     = (unsigned short*)(base + 14974976);   // 4096x1536
  float*          Ob    = (float*)(base + 27557888);            // 4096x512 f32
  float*          lin   = (float*)(base + 35946496);            // 4096x512 f32

  prep_kernel<<<1280 + NT_TOK + NV_TOK, 256, 0, stream>>>(
      text, video, ln1_g, ln1_b, Wq, Wk, Wv, Wo, Wl, Wbf, tn_bf, vn_bf);

  qkv_kernel<<<704, 256, 0, stream>>>(tn_bf, vn_bf, Wq_bf, Wk_bf, Wv_bf,
                                      bq, bk, bv, Q_bf, K_bf, V_bf, stats);

  sgemm_softmax<<<1216, 256, 0, stream>>>(Q_bf, K_bf, V_bf, Wo_bf, P, W2);

  // Ob = P @ W2^T + bo  (+ LN2 stats atomics); 64x32 tiles, 1024 blocks
  gemm_pvo<<<dim3(64, 16), 256, 0, stream>>>(P, W2, bo, Ob, stats);

  // lin = LN2(Ob) @ Wl^T + bl  (LN2 in A-staging); 64x32 tiles, 1024 blocks
  gemm_lnl<<<dim3(64, 16), 256, 0, stream>>>(Ob, stats, ln2_g, ln2_b, Wl_bf,
                                             bl, lin);

  // out = LN3(LN2(Ob) + lin)
  ln3_kernel<<<NT_TOK, 256, 0, stream>>>(Ob, stats, lin, ln2_g, ln2_b,
                                         ln3_g, ln3_b, out);
}

// Round 12
// 161.224 us; speedup vs baseline: 1.0608x; 1.0608x over previous
//
#include <hip/hip_runtime.h>
#include <math.h>

#define EMBED 512
#define HD 256
#define FR 12
#define NV 64
#define NT_TOK 4096
#define NV_TOK 768

typedef __attribute__((ext_vector_type(8))) short short8;
typedef __attribute__((ext_vector_type(4))) float f32x4;

__device__ __forceinline__ unsigned int f2bf(float f) {
  unsigned int u = __float_as_uint(f);
  u += 0x7FFFu + ((u >> 16) & 1u);   // RNE
  return u >> 16;
}
__device__ __forceinline__ void async_cp16(void* lds, const void* g) {
  __builtin_amdgcn_global_load_lds(
      (const __attribute__((address_space(1))) void*)g,
      (__attribute__((address_space(3))) void*)lds, 16, 0, 0);
}

// ===== 64x64 GEMM core: BK=64, 4 waves of 32x32, dbuf 1-sync ===============
__device__ __forceinline__ void gemm64_core(
    const unsigned short* __restrict__ Ab, int lda,
    const unsigned short* __restrict__ Bb, int ldb,
    int m0, int n0, int K,
    unsigned short* __restrict__ As, unsigned short* __restrict__ Bs,
    f32x4 acc[2][2]) {
  int tid = threadIdx.x;
  int w = tid >> 6, lane = tid & 63;
  int lr = lane & 15, quad = lane >> 4;
  int wm = (w >> 1) * 32, wn = (w & 1) * 32;
  int rowS[2], cgS[2];
  #pragma unroll
  for (int i = 0; i < 2; ++i) {
    int s = tid + i * 256;
    rowS[i] = s >> 3; cgS[i] = (s & 7) ^ (rowS[i] & 7);
  }
  int nk = K >> 6;
  #pragma unroll
  for (int i = 0; i < 2; ++i) {
    async_cp16(&As[(tid + i * 256) * 8],
               Ab + (size_t)(m0 + rowS[i]) * lda + cgS[i] * 8);
    async_cp16(&Bs[(tid + i * 256) * 8],
               Bb + (size_t)(n0 + rowS[i]) * ldb + cgS[i] * 8);
  }
  for (int k = 0; k < nk; ++k) {
    int cur = k & 1;
    __syncthreads();
    if (k + 1 < nk) {
      int nxt = cur ^ 1, koff = (k + 1) << 6;
      #pragma unroll
      for (int i = 0; i < 2; ++i) {
        async_cp16(&As[nxt * 4096 + (tid + i * 256) * 8],
                   Ab + (size_t)(m0 + rowS[i]) * lda + koff + cgS[i] * 8);
        async_cp16(&Bs[nxt * 4096 + (tid + i * 256) * 8],
                   Bb + (size_t)(n0 + rowS[i]) * ldb + koff + cgS[i] * 8);
      }
    }
    const unsigned short* Ac = As + cur * 4096;
    const unsigned short* Bc = Bs + cur * 4096;
    #pragma unroll
    for (int kk = 0; kk < 2; ++kk) {
      int sw = ((kk * 4 + quad) ^ (lr & 7)) * 8;
      short8 a0 = *(const short8*)&Ac[(wm + lr) * 64 + sw];
      short8 a1 = *(const short8*)&Ac[(wm + 16 + lr) * 64 + sw];
      short8 b0 = *(const short8*)&Bc[(wn + lr) * 64 + sw];
      short8 b1 = *(const short8*)&Bc[(wn + 16 + lr) * 64 + sw];
      acc[0][0] = __builtin_amdgcn_mfma_f32_16x16x32_bf16(a0, b0, acc[0][0], 0, 0, 0);
      acc[0][1] = __builtin_amdgcn_mfma_f32_16x16x32_bf16(a0, b1, acc[0][1], 0, 0, 0);
      acc[1][0] = __builtin_amdgcn_mfma_f32_16x16x32_bf16(a1, b0, acc[1][0], 0, 0, 0);
      acc[1][1] = __builtin_amdgcn_mfma_f32_16x16x32_bf16(a1, b1, acc[1][1], 0, 0, 0);
    }
  }
}

// ===== fused QKV projection (+ zero the LN2 stats buffer) ==================
__global__ __launch_bounds__(256, 4) void qkv_kernel(
    const unsigned short* __restrict__ tn, const unsigned short* __restrict__ vn,
    const unsigned short* __restrict__ Wq, const unsigned short* __restrict__ Wk,
    const unsigned short* __restrict__ Wv,
    const float* __restrict__ bq, const float* __restrict__ bk,
    const float* __restrict__ bv,
    unsigned short* __restrict__ Q, unsigned short* __restrict__ Kout,
    unsigned short* __restrict__ V, float* __restrict__ stats) {
  __shared__ __align__(16) unsigned short As[2 * 4096];
  __shared__ __align__(16) unsigned short Bs[2 * 4096];
  int bid = blockIdx.x;
  if (bid < 32) stats[bid * 256 + threadIdx.x] = 0.0f;  // 8192 floats
  const unsigned short *Ap, *Bp;
  const float* bias;
  unsigned short* outp;
  int m0, n0;
  if (bid < 512) {            // Q
    Ap = tn; Bp = Wq; bias = bq; outp = Q;
    m0 = (bid >> 3) * 64; n0 = (bid & 7) * 64;
  } else if (bid < 608) {     // K
    int i = bid - 512;
    Ap = vn; Bp = Wk; bias = bk; outp = Kout;
    m0 = (i >> 3) * 64; n0 = (i & 7) * 64;
  } else {                    // V
    int i = bid - 608;
    Ap = vn; Bp = Wv; bias = bv; outp = V;
    m0 = (i >> 3) * 64; n0 = (i & 7) * 64;
  }
  f32x4 acc[2][2] = {};
  gemm64_core(Ap, EMBED, Bp, EMBED, m0, n0, EMBED, As, Bs, acc);
  int w = threadIdx.x >> 6, lane = threadIdx.x & 63;
  int lr = lane & 15, quad = lane >> 4;
  int wm = (w >> 1) * 32, wn = (w & 1) * 32;
  #pragma unroll
  for (int j = 0; j < 2; ++j) {
    int col = n0 + wn + j * 16 + lr;
    float bvv = bias[col];
    #pragma unroll
    for (int i = 0; i < 2; ++i) {
      int rbase = m0 + wm + i * 16 + quad * 4;
      #pragma unroll
      for (int r = 0; r < 4; ++r)
        outp[(size_t)(rbase + r) * EMBED + col] =
            (unsigned short)f2bf(acc[i][j][r] + bvv);
    }
  }
}

// ===== S-GEMM + softmax -> P [4096][1536]; plus W2 = Wo_h @ V_h^T ==========
__global__ __launch_bounds__(256, 4) void sgemm_softmax(
    const unsigned short* __restrict__ Q, const unsigned short* __restrict__ Kb,
    const unsigned short* __restrict__ V, const unsigned short* __restrict__ Wo,
    unsigned short* __restrict__ P, unsigned short* __restrict__ W2) {
  __shared__ __align__(16) char smem[40960];
  int tid = threadIdx.x;
  int w = tid >> 6, lane = tid & 63;
  int lr = lane & 15, quad = lane >> 4;
  int bid = blockIdx.x;

  if (bid >= 1024) {  // ---- W2 job (64x64, K=256) ----
    int j = bid - 1024;
    int h = j / 96, i = j % 96;
    int m0 = (i / 12) * 64, n0 = (i % 12) * 64;
    unsigned short* As = (unsigned short*)smem;
    unsigned short* Bs = (unsigned short*)(smem + 16384);
    f32x4 acc[2][2] = {};
    gemm64_core(Wo + h * HD, EMBED, V + h * HD, EMBED, m0, n0, HD, As, Bs, acc);
    int wm = (w >> 1) * 32, wn = (w & 1) * 32;
    #pragma unroll
    for (int j2 = 0; j2 < 2; ++j2) {
      int col = n0 + wn + j2 * 16 + lr;
      #pragma unroll
      for (int i2 = 0; i2 < 2; ++i2) {
        int rbase = m0 + wm + i2 * 16 + quad * 4;
        #pragma unroll
        for (int r = 0; r < 4; ++r)
          W2[(size_t)(rbase + r) * 1536 + h * 768 + col] =
              (unsigned short)f2bf(acc[i2][j2][r]);
      }
    }
    return;
  }

  // ---- S-softmax job: 64x96 tile ----
  unsigned short* As = (unsigned short*)smem;            // 2 x 4096
  unsigned short* Bs = (unsigned short*)(smem + 16384);  // 2 x 6144
  int wm = (w >> 1) * 32, wn = (w & 1) * 48;
  int h = bid >> 9, rem = bid & 511;
  int m0 = (rem >> 3) * 64, n0 = (rem & 7) * 96;
  const unsigned short* Ab = Q + h * HD;
  const unsigned short* Bb = Kb + h * HD;
  int rowA[2], cgA[2], rowB[3], cgB[3];
  #pragma unroll
  for (int i = 0; i < 2; ++i) {
    int s = tid + i * 256;
    rowA[i] = s >> 3; cgA[i] = (s & 7) ^ (rowA[i] & 7);
  }
  #pragma unroll
  for (int i = 0; i < 3; ++i) {
    int s = tid + i * 256;
    rowB[i] = s >> 3; cgB[i] = (s & 7) ^ (rowB[i] & 7);
  }
  f32x4 acc[2][3] = {};
  const int nk = HD >> 6;  // 4
  #pragma unroll
  for (int i = 0; i < 2; ++i)
    async_cp16(&As[(tid + i * 256) * 8],
               Ab + (size_t)(m0 + rowA[i]) * EMBED + cgA[i] * 8);
  #pragma unroll
  for (int i = 0; i < 3; ++i)
    async_cp16(&Bs[(tid + i * 256) * 8],
               Bb + (size_t)(n0 + rowB[i]) * EMBED + cgB[i] * 8);
  for (int k = 0; k < nk; ++k) {
    int cur = k & 1;
    __syncthreads();
    if (k + 1 < nk) {
      int nxt = cur ^ 1, koff = (k + 1) << 6;
      #pragma unroll
      for (int i = 0; i < 2; ++i)
        async_cp16(&As[nxt * 4096 + (tid + i * 256) * 8],
                   Ab + (size_t)(m0 + rowA[i]) * EMBED + koff + cgA[i] * 8);
      #pragma unroll
      for (int i = 0; i < 3; ++i)
        async_cp16(&Bs[nxt * 6144 + (tid + i * 256) * 8],
                   Bb + (size_t)(n0 + rowB[i]) * EMBED + koff + cgB[i] * 8);
    }
    const unsigned short* Ac = As + cur * 4096;
    const unsigned short* Bc = Bs + cur * 6144;
    #pragma unroll
    for (int kk = 0; kk < 2; ++kk) {
      int sw = ((kk * 4 + quad) ^ (lr & 7)) * 8;
      short8 a0 = *(const short8*)&Ac[(wm + lr) * 64 + sw];
      short8 a1 = *(const short8*)&Ac[(wm + 16 + lr) * 64 + sw];
      short8 b0 = *(const short8*)&Bc[(wn + lr) * 64 + sw];
      short8 b1 = *(const short8*)&Bc[(wn + 16 + lr) * 64 + sw];
      short8 b2 = *(const short8*)&Bc[(wn + 32 + lr) * 64 + sw];
      acc[0][0] = __builtin_amdgcn_mfma_f32_16x16x32_bf16(a0, b0, acc[0][0], 0, 0, 0);
      acc[0][1] = __builtin_amdgcn_mfma_f32_16x16x32_bf16(a0, b1, acc[0][1], 0, 0, 0);
      acc[0][2] = __builtin_amdgcn_mfma_f32_16x16x32_bf16(a0, b2, acc[0][2], 0, 0, 0);
      acc[1][0] = __builtin_amdgcn_mfma_f32_16x16x32_bf16(a1, b0, acc[1][0], 0, 0, 0);
      acc[1][1] = __builtin_amdgcn_mfma_f32_16x16x32_bf16(a1, b1, acc[1][1], 0, 0, 0);
      acc[1][2] = __builtin_amdgcn_mfma_f32_16x16x32_bf16(a1, b2, acc[1][2], 0, 0, 0);
    }
  }
  __syncthreads();
  float* Sx = (float*)smem;  // [64][100]
  #pragma unroll
  for (int j = 0; j < 3; ++j) {
    int col = wn + j * 16 + lr;
    #pragma unroll
    for (int i = 0; i < 2; ++i) {
      int rbase = wm + i * 16 + quad * 4;
      #pragma unroll
      for (int r = 0; r < 4; ++r) Sx[(rbase + r) * 100 + col] = acc[i][j][r];
    }
  }
  __syncthreads();
  #pragma unroll
  for (int gi = 0; gi < 2; ++gi) {
    int g = tid * 2 + gi;
    int row = g >> 3, gr = g & 7;
    const float* sp = Sx + row * 100 + gr * 12;
    float v[12];
    float m = -1e30f;
    #pragma unroll
    for (int f = 0; f < FR; ++f) { v[f] = sp[f] * 0.0625f; m = fmaxf(m, v[f]); }
    float s = 0.f;
    #pragma unroll
    for (int f = 0; f < FR; ++f) { v[f] = __expf(v[f] - m); s += v[f]; }
    float inv = (1.0f / NV) / s;
    unsigned short* pp = P + (size_t)(m0 + row) * 1536 + h * 768 + n0 + gr * 12;
    #pragma unroll
    for (int ii = 0; ii < 6; ++ii) {
      unsigned int lo = f2bf(v[2 * ii] * inv), hi = f2bf(v[2 * ii + 1] * inv);
      *(unsigned int*)(pp + 2 * ii) = lo | (hi << 16);
    }
  }
}

// ===== PV+O GEMM (64x64, K=1536) with LN2-stats atomics in epilogue ========
__global__ __launch_bounds__(256, 4) void gemm_pvo(
    const unsigned short* __restrict__ P, const unsigned short* __restrict__ W2,
    const float* __restrict__ bo, float* __restrict__ Ob,
    float* __restrict__ stats) {
  __shared__ __align__(16) unsigned short As[2 * 4096];
  __shared__ __align__(16) unsigned short Bs[2 * 4096];
  f32x4 acc[2][2] = {};
  int m0 = blockIdx.x * 64, n0 = blockIdx.y * 64;
  gemm64_core(P, 1536, W2, 1536, m0, n0, 1536, As, Bs, acc);
  int w = threadIdx.x >> 6, lane = threadIdx.x & 63;
  int lr = lane & 15, quad = lane >> 4;
  int wm = (w >> 1) * 32, wn = (w & 1) * 32;
  float rs[2][4] = {}, rq[2][4] = {};
  #pragma unroll
  for (int j = 0; j < 2; ++j) {
    int col = n0 + wn + j * 16 + lr;
    float bv = bo[col];
    #pragma unroll
    for (int i = 0; i < 2; ++i) {
      int rbase = m0 + wm + i * 16 + quad * 4;
      #pragma unroll
      for (int r = 0; r < 4; ++r) {
        float v = acc[i][j][r] + bv;
        Ob[(size_t)(rbase + r) * EMBED + col] = v;
        rs[i][r] += v;
        rq[i][r] += v * v;
      }
    }
  }
  #pragma unroll
  for (int off = 8; off > 0; off >>= 1) {
    #pragma unroll
    for (int i = 0; i < 2; ++i)
      #pragma unroll
      for (int r = 0; r < 4; ++r) {
        rs[i][r] += __shfl_down(rs[i][r], off, 16);
        rq[i][r] += __shfl_down(rq[i][r], off, 16);
      }
  }
  if (lr == 0) {
    #pragma unroll
    for (int i = 0; i < 2; ++i) {
      #pragma unroll
      for (int r = 0; r < 4; ++r) {
        int row = m0 + wm + i * 16 + quad * 4 + r;
        atomicAdd(&stats[row * 2], rs[i][r]);
        atomicAdd(&stats[row * 2 + 1], rq[i][r]);
      }
    }
  }
}

// ===== L-GEMM (64x64) with LN2 applied during A-staging ====================
__global__ __launch_bounds__(256) void gemm_lnl(
    const float* __restrict__ Ob, const float* __restrict__ stats,
    const float* __restrict__ g2, const float* __restrict__ b2,
    const unsigned short* __restrict__ Wl, const float* __restrict__ bl,
    float* __restrict__ lin) {
  __shared__ __align__(16) unsigned short As[2 * 4096];
  __shared__ __align__(16) unsigned short Bs[2 * 4096];
  int tid = threadIdx.x;
  int w = tid >> 6, lane = tid & 63;
  int lr = lane & 15, quad = lane >> 4;
  int wm = (w >> 1) * 32, wn = (w & 1) * 32;
  int m0 = blockIdx.x * 64, n0 = blockIdx.y * 64;
  int rowS[2], cgS[2];
  float mu[2], rstd[2];
  #pragma unroll
  for (int i = 0; i < 2; ++i) {
    int s = tid + i * 256;
    rowS[i] = s >> 3; cgS[i] = (s & 7) ^ (rowS[i] & 7);
    float s1 = stats[(m0 + rowS[i]) * 2];
    float s2 = stats[(m0 + rowS[i]) * 2 + 1];
    float m = s1 * (1.0f / EMBED);
    mu[i] = m;
    rstd[i] = rsqrtf(s2 * (1.0f / EMBED) - m * m + 1e-5f);
  }
  f32x4 acc[2][2] = {};
  const int nk = EMBED >> 6;  // 8

  #define STAGE_A(buf, koff)                                                  \
    {                                                                         \
      _Pragma("unroll") for (int i = 0; i < 2; ++i) {                         \
        const float* src = Ob + (size_t)(m0 + rowS[i]) * EMBED + (koff) +     \
                           cgS[i] * 8;                                        \
        const float* gp = g2 + (koff) + cgS[i] * 8;                           \
        const float* bp = b2 + (koff) + cgS[i] * 8;                           \
        float4 x0 = *(const float4*)src;                                      \
        float4 x1 = *(const float4*)(src + 4);                                \
        float4 ga = *(const float4*)gp;                                       \
        float4 gb = *(const float4*)(gp + 4);                                 \
        float4 ba = *(const float4*)bp;                                       \
        float4 bb = *(const float4*)(bp + 4);                                 \
        float y0 = (x0.x - mu[i]) * rstd[i] * ga.x + ba.x;                    \
        float y1 = (x0.y - mu[i]) * rstd[i] * ga.y + ba.y;                    \
        float y2 = (x0.z - mu[i]) * rstd[i] * ga.z + ba.z;                    \
        float y3 = (x0.w - mu[i]) * rstd[i] * ga.w + ba.w;                    \
        float y4 = (x1.x - mu[i]) * rstd[i] * gb.x + bb.x;                    \
        float y5 = (x1.y - mu[i]) * rstd[i] * gb.y + bb.y;                    \
        float y6 = (x1.z - mu[i]) * rstd[i] * gb.z + bb.z;                    \
        float y7 = (x1.w - mu[i]) * rstd[i] * gb.w + bb.w;                    \
        uint4 pk;                                                             \
        pk.x = f2bf(y0) | (f2bf(y1) << 16);                                   \
        pk.y = f2bf(y2) | (f2bf(y3) << 16);                                   \
        pk.z = f2bf(y4) | (f2bf(y5) << 16);                                   \
        pk.w = f2bf(y6) | (f2bf(y7) << 16);                                   \
        *(uint4*)&As[(buf)*4096 + (tid + i * 256) * 8] = pk;                  \
      }                                                                       \
    }

  STAGE_A(0, 0)
  #pragma unroll
  for (int i = 0; i < 2; ++i)
    async_cp16(&Bs[(tid + i * 256) * 8],
               Wl + (size_t)(n0 + rowS[i]) * EMBED + cgS[i] * 8);
  for (int k = 0; k < nk; ++k) {
    int cur = k & 1;
    __syncthreads();
    if (k + 1 < nk) {
      int nxt = cur ^ 1, koff = (k + 1) << 6;
      STAGE_A(nxt, koff)
      #pragma unroll
      for (int i = 0; i < 2; ++i)
        async_cp16(&Bs[nxt * 4096 + (tid + i * 256) * 8],
                   Wl + (size_t)(n0 + rowS[i]) * EMBED + koff + cgS[i] * 8);
    }
    const unsigned short* Ac = As + cur * 4096;
    const unsigned short* Bc = Bs + cur * 4096;
    #pragma unroll
    for (int kk = 0; kk < 2; ++kk) {
      int sw = ((kk * 4 + quad) ^ (lr & 7)) * 8;
      short8 a0 = *(const short8*)&Ac[(wm + lr) * 64 + sw];
      short8 a1 = *(const short8*)&Ac[(wm + 16 + lr) * 64 + sw];
      short8 b0 = *(const short8*)&Bc[(wn + lr) * 64 + sw];
      short8 b1 = *(const short8*)&Bc[(wn + 16 + lr) * 64 + sw];
      acc[0][0] = __builtin_amdgcn_mfma_f32_16x16x32_bf16(a0, b0, acc[0][0], 0, 0, 0);
      acc[0][1] = __builtin_amdgcn_mfma_f32_16x16x32_bf16(a0, b1, acc[0][1], 0, 0, 0);
      acc[1][0] = __builtin_amdgcn_mfma_f32_16x16x32_bf16(a1, b0, acc[1][0], 0, 0, 0);
      acc[1][1] = __builtin_amdgcn_mfma_f32_16x16x32_bf16(a1, b1, acc[1][1], 0, 0, 0);
    }
  }
  #pragma unroll
  for (int j = 0; j < 2; ++j) {
    int col = n0 + wn + j * 16 + lr;
    float bv = bl[col];
    #pragma unroll
    for (int i = 0; i < 2; ++i) {
      int rbase = m0 + wm + i * 16 + quad * 4;
      #pragma unroll
      for (int r = 0; r < 4; ++r)
        lin[(size_t)(rbase + r) * EMBED + col] = acc[i][j][r] + bv;
    }
  }
  #undef STAGE_A
}

// ===== final: out = LN3( LN2(Ob) + lin ), one wave per row =================
__global__ __launch_bounds__(256) void ln3_kernel(
    const float* __restrict__ Ob, const float* __restrict__ stats,
    const float* __restrict__ lin,
    const float* __restrict__ g2, const float* __restrict__ b2,
    const float* __restrict__ g3, const float* __restrict__ b3,
    float* __restrict__ out) {
  int row = blockIdx.x * 4 + (threadIdx.x >> 6);
  int lane = threadIdx.x & 63;
  int c = lane * 8;
  float s1 = stats[row * 2], s2v = stats[row * 2 + 1];
  float mu2 = s1 * (1.0f / EMBED);
  float rstd2 = rsqrtf(s2v * (1.0f / EMBED) - mu2 * mu2 + 1e-5f);
  const float* xr = Ob + (size_t)row * EMBED + c;
  const float* lr_ = lin + (size_t)row * EMBED + c;
  float4 x0 = *(const float4*)xr, x1 = *(const float4*)(xr + 4);
  float4 l0 = *(const float4*)lr_, l1 = *(const float4*)(lr_ + 4);
  float4 g2a = *(const float4*)(g2 + c), g2b = *(const float4*)(g2 + c + 4);
  float4 b2a = *(const float4*)(b2 + c), b2b = *(const float4*)(b2 + c + 4);
  float v[8];
  v[0] = (x0.x - mu2) * rstd2 * g2a.x + b2a.x + l0.x;
  v[1] = (x0.y - mu2) * rstd2 * g2a.y + b2a.y + l0.y;
  v[2] = (x0.z - mu2) * rstd2 * g2a.z + b2a.z + l0.z;
  v[3] = (x0.w - mu2) * rstd2 * g2a.w + b2a.w + l0.w;
  v[4] = (x1.x - mu2) * rstd2 * g2b.x + b2b.x + l1.x;
  v[5] = (x1.y - mu2) * rstd2 * g2b.y + b2b.y + l1.y;
  v[6] = (x1.z - mu2) * rstd2 * g2b.z + b2b.z + l1.z;
  v[7] = (x1.w - mu2) * rstd2 * g2b.w + b2b.w + l1.w;
  float s = 0.f, q = 0.f;
  #pragma unroll
  for (int i = 0; i < 8; ++i) { s += v[i]; q += v[i] * v[i]; }
  #pragma unroll
  for (int off = 32; off > 0; off >>= 1) {
    s += __shfl_down(s, off, 64);
    q += __shfl_down(q, off, 64);
  }
  s = __shfl(s, 0, 64);
  q = __shfl(q, 0, 64);
  float mean = s * (1.0f / EMBED);
  float rstd = rsqrtf(q * (1.0f / EMBED) - mean * mean + 1e-5f);
  float4 g3a = *(const float4*)(g3 + c), g3b = *(const float4*)(g3 + c + 4);
  float4 b3a = *(const float4*)(b3 + c), b3b = *(const float4*)(b3 + c + 4);
  float4 o0, o1;
  o0.x = (v[0] - mean) * rstd * g3a.x + b3a.x;
  o0.y = (v[1] - mean) * rstd * g3a.y + b3a.y;
  o0.z = (v[2] - mean) * rstd * g3a.z + b3a.z;
  o0.w = (v[3] - mean) * rstd * g3a.w + b3a.w;
  o1.x = (v[4] - mean) * rstd * g3b.x + b3b.x;
  o1.y = (v[5] - mean) * rstd * g3b.y + b3b.y;
  o1.z = (v[6] - mean) * rstd * g3b.z + b3b.z;
  o1.w = (v[7] - mean) * rstd * g3b.w + b3b.w;
  float* orow = out + (size_t)row * EMBED + c;
  *(float4*)orow = o0;
  *(float4*)(orow + 4) = o1;
}

// ===== prep: weight fp32->bf16 + LN1 (one wave per row) ====================
__global__ __launch_bounds__(256) void prep_kernel(
    const float* __restrict__ text, const float* __restrict__ video,
    const float* __restrict__ g, const float* __restrict__ b,
    const float* __restrict__ Wq, const float* __restrict__ Wk,
    const float* __restrict__ Wv, const float* __restrict__ Wo,
    const float* __restrict__ Wl, unsigned short* __restrict__ Wbf,
    unsigned short* __restrict__ tn, unsigned short* __restrict__ vn) {
  int bid = blockIdx.x;
  if (bid < 1280) {  // weight convert: one float4 per thread
    int i = bid * 256 + threadIdx.x;
    const float* srcs[5] = {Wq, Wk, Wv, Wo, Wl};
    const float* src = srcs[i >> 16];
    float4 v = ((const float4*)src)[i & 65535];
    uint2 o;
    o.x = f2bf(v.x) | (f2bf(v.y) << 16);
    o.y = f2bf(v.z) | (f2bf(v.w) << 16);
    ((uint2*)Wbf)[i] = o;
    return;
  }
  // LN1: 4864 rows, 4 rows/block (one wave each)
  int row = (bid - 1280) * 4 + (threadIdx.x >> 6);
  int lane = threadIdx.x & 63;
  int c = lane * 8;
  const float* xr;
  unsigned short* outb;
  if (row < NT_TOK) {
    xr = text + (size_t)row * EMBED + c;
    outb = tn + (size_t)row * EMBED + c;
  } else {
    xr = video + (size_t)(row - NT_TOK) * EMBED + c;
    outb = vn + (size_t)(row - NT_TOK) * EMBED + c;
  }
  float4 x0 = *(const float4*)xr, x1 = *(const float4*)(xr + 4);
  float v[8] = {x0.x, x0.y, x0.z, x0.w, x1.x, x1.y, x1.z, x1.w};
  float s = 0.f, q = 0.f;
  #pragma unroll
  for (int i = 0; i < 8; ++i) { s += v[i]; q += v[i] * v[i]; }
  #pragma unroll
  for (int off = 32; off > 0; off >>= 1) {
    s += __shfl_down(s, off, 64);
    q += __shfl_down(q, off, 64);
  }
  s = __shfl(s, 0, 64);
  q = __shfl(q, 0, 64);
  float mean = s * (1.0f / EMBED);
  float rstd = rsqrtf(q * (1.0f / EMBED) - mean * mean + 1e-5f);
  float4 ga = *(const float4*)(g + c), gb = *(const float4*)(g + c + 4);
  float4 ba = *(const float4*)(b + c), bb = *(const float4*)(b + c + 4);
  float gg[8] = {ga.x, ga.y, ga.z, ga.w, gb.x, gb.y, gb.z, gb.w};
  float bbv[8] = {ba.x, ba.y, ba.z, ba.w, bb.x, bb.y, bb.z, bb.w};
  uint4 pk;
  unsigned int h[8];
  #pragma unroll
  for (int i = 0; i < 8; ++i)
    h[i] = f2bf((v[i] - mean) * rstd * gg[i] + bbv[i]);
  pk.x = h[0] | (h[1] << 16);
  pk.y = h[2] | (h[3] << 16);
  pk.z = h[4] | (h[5] << 16);
  pk.w = h[6] | (h[7] << 16);
  *(uint4*)outb = pk;
}

// ===== launch ==============================================================
extern "C" void kernel_launch(void* const* d_in, const int* in_sizes, int n_in,
                              void* d_out, int out_size, void* d_ws, size_t ws_size,
                              hipStream_t stream) {
  (void)in_sizes; (void)n_in; (void)out_size; (void)ws_size;
  const float* text  = (const float*)d_in[0];
  const float* video = (const float*)d_in[1];
  const float* ln1_g = (const float*)d_in[2];
  const float* ln1_b = (const float*)d_in[3];
  const float* Wq = (const float*)d_in[4];
  const float* bq = (const float*)d_in[5];
  const float* Wk = (const float*)d_in[6];
  const float* bk = (const float*)d_in[7];
  const float* Wv = (const float*)d_in[8];
  const float* bv = (const float*)d_in[9];
  const float* Wo = (const float*)d_in[10];
  const float* bo = (const float*)d_in[11];
  const float* Wl = (const float*)d_in[12];
  const float* bl = (const float*)d_in[13];
  const float* ln2_g = (const float*)d_in[14];
  const float* ln2_b = (const float*)d_in[15];
  const float* ln3_g = (const float*)d_in[16];
  const float* ln3_b = (const float*)d_in[17];
  float* out = (float*)d_out;

  // ---- workspace layout (44.3 MB, no aliasing) ----
  char* base = (char*)d_ws;
  unsigned short* Wbf   = (unsigned short*)base;                // 2.62 MB
  unsigned short* Wq_bf = Wbf + 0 * 262144;
  unsigned short* Wk_bf = Wbf + 1 * 262144;
  unsigned short* Wv_bf = Wbf + 2 * 262144;
  unsigned short* Wo_bf = Wbf + 3 * 262144;
  unsigned short* Wl_bf = Wbf + 4 * 262144;
  unsigned short* W2    = (unsigned short*)(base + 2621440);    // 512x1536
  float*          stats = (float*)(base + 4194304);             // 4096x2
  unsigned short* tn_bf = (unsigned short*)(base + 4227072);    // 4096x512
  unsigned short* vn_bf = (unsigned short*)(base + 8421376);    // 768x512
  unsigned short* Q_bf  = (unsigned short*)(base + 9207808);    // 4096x512
  unsigned short* K_bf  = (unsigned short*)(base + 13402112);   // 768x512
  unsigned short* V_bf  = (unsigned short*)(base + 14188544);   // 768x512
  unsigned short* P     = (unsigned short*)(base + 14974976);   // 4096x1536
  float*          Ob    = (float*)(base + 27557888);            // 4096x512 f32
  float*          lin   = (float*)(base + 35946496);            // 4096x512 f32

  // prep: 1280 weight-cvt blocks + 1216 LN blocks (4 rows each)
  prep_kernel<<<1280 + 1216, 256, 0, stream>>>(
      text, video, ln1_g, ln1_b, Wq, Wk, Wv, Wo, Wl, Wbf, tn_bf, vn_bf);

  qkv_kernel<<<704, 256, 0, stream>>>(tn_bf, vn_bf, Wq_bf, Wk_bf, Wv_bf,
                                      bq, bk, bv, Q_bf, K_bf, V_bf, stats);

  sgemm_softmax<<<1216, 256, 0, stream>>>(Q_bf, K_bf, V_bf, Wo_bf, P, W2);

  // Ob = P @ W2^T + bo  (+ LN2 stats atomics)
  gemm_pvo<<<dim3(64, 8), 256, 0, stream>>>(P, W2, bo, Ob, stats);

  // lin = LN2(Ob) @ Wl^T + bl  (LN2 applied in A-staging)
  gemm_lnl<<<dim3(64, 8), 256, 0, stream>>>(Ob, stats, ln2_g, ln2_b, Wl_bf,
                                            bl, lin);

  // out = LN3(LN2(Ob) + lin)  — one wave per row
  ln3_kernel<<<1024, 256, 0, stream>>>(Ob, stats, lin, ln2_g, ln2_b,
                                       ln3_g, ln3_b, out);
}